// Round 1
// baseline (1281.291 us; speedup 1.0000x reference)
//
#include <hip/hip_runtime.h>
#include <hip/hip_bf16.h>
#include <math.h>

#define T_TOK 4096
#define HID   4096
#define NHQ   32
#define NKVH  8
#define HDIM  128
#define SEQ   1024
#define NBATCH 4

typedef __attribute__((ext_vector_type(8))) short bf16x8;
typedef __attribute__((ext_vector_type(4))) float f32x4;

__device__ __forceinline__ unsigned short f2bf(float f) {
  union { float f; unsigned int u; } x; x.f = f;
  unsigned int r = x.u + 0x7FFFu + ((x.u >> 16) & 1u);
  return (unsigned short)(r >> 16);
}

// ---------------- cast fp32 -> bf16, 4 elems/thread ----------------
__global__ __launch_bounds__(256) void cast_bf16_k(const float* __restrict__ in,
                                                   unsigned short* __restrict__ out,
                                                   int n4) {
  int i = blockIdx.x * 256 + threadIdx.x;
  if (i >= n4) return;
  float4 f = ((const float4*)in)[i];
  ushort4 o;
  o.x = f2bf(f.x); o.y = f2bf(f.y); o.z = f2bf(f.z); o.w = f2bf(f.w);
  ((ushort4*)out)[i] = o;
}

// ---------------- GEMM: C[M,N] = A[M,K] @ B[N,K]^T (bf16 in, fp32/bf16 out) ----
// 128x128 tile, BK=64, 4 waves of 64x64, 16x16x32 bf16 MFMA.
// LDS xor-swizzle: chunk_phys = chunk_logical ^ (row & 7)  -> 2-way reads (free).
template<bool OUT_BF16>
__global__ __launch_bounds__(256) void gemm_bt_k(const unsigned short* __restrict__ A,
                                                 const unsigned short* __restrict__ B,
                                                 void* __restrict__ Cv,
                                                 int M, int N, int K) {
  __shared__ unsigned short As[128][64];
  __shared__ unsigned short Bs[128][64];
  const int tid  = threadIdx.x;
  const int lane = tid & 63;
  const int wave = tid >> 6;
  const int m16  = lane & 15, quad = lane >> 4;
  const int wm   = (wave >> 1) * 64, wn = (wave & 1) * 64;
  const long rowBase = (long)blockIdx.y * 128;
  const long colBase = (long)blockIdx.x * 128;

  f32x4 acc[4][4] = {};

  for (int k0 = 0; k0 < K; k0 += 64) {
    __syncthreads();
#pragma unroll
    for (int l = tid; l < 1024; l += 256) {
      int row = l >> 3, seg = l & 7;
      uint4 da = *(const uint4*)(A + (rowBase + row) * K + k0 + seg * 8);
      *(uint4*)(&As[row][(seg ^ (row & 7)) * 8]) = da;
      uint4 db = *(const uint4*)(B + (colBase + row) * K + k0 + seg * 8);
      *(uint4*)(&Bs[row][(seg ^ (row & 7)) * 8]) = db;
    }
    __syncthreads();
#pragma unroll
    for (int kk = 0; kk < 2; ++kk) {
      bf16x8 af[4], bfr[4];
#pragma unroll
      for (int i = 0; i < 4; ++i) {
        int row = wm + i * 16 + m16;
        af[i] = *(const bf16x8*)(&As[row][((kk * 4 + quad) ^ (row & 7)) * 8]);
      }
#pragma unroll
      for (int j = 0; j < 4; ++j) {
        int row = wn + j * 16 + m16;
        bfr[j] = *(const bf16x8*)(&Bs[row][((kk * 4 + quad) ^ (row & 7)) * 8]);
      }
#pragma unroll
      for (int i = 0; i < 4; ++i)
#pragma unroll
        for (int j = 0; j < 4; ++j)
          acc[i][j] = __builtin_amdgcn_mfma_f32_16x16x32_bf16(af[i], bfr[j], acc[i][j], 0, 0, 0);
    }
  }
#pragma unroll
  for (int i = 0; i < 4; ++i) {
#pragma unroll
    for (int j = 0; j < 4; ++j) {
      long r0 = rowBase + wm + i * 16 + quad * 4;
      long c  = colBase + wn + j * 16 + m16;
#pragma unroll
      for (int r = 0; r < 4; ++r) {
        float v = acc[i][j][r];
        if (OUT_BF16) ((unsigned short*)Cv)[(r0 + r) * N + c] = f2bf(v);
        else          ((float*)Cv)[(r0 + r) * N + c] = v;
      }
    }
  }
}

// ---------------- RoPE (faithful to reference: repeat-by-2 freqs + rotate-half) --
template<int NHEADS>
__global__ __launch_bounds__(256) void rope_k(const float* __restrict__ in,
                                              unsigned short* __restrict__ out,
                                              const int* __restrict__ pos) {
  int idx = blockIdx.x * 256 + threadIdx.x;  // exact grid: T*NHEADS*64
  int d  = idx & 63;
  int th = idx >> 6;
  int t  = th / NHEADS;
  int hh = th - t * NHEADS;
  int p  = pos[t];
  p = p < 0 ? 0 : (p > SEQ - 1 ? SEQ - 1 : p);
  float pf = (float)p;
  long base = (long)t * (NHEADS * HDIM) + hh * HDIM + d;
  float lo = in[base], hi = in[base + 64];
  const float c0 = -13.287712379549449f / 64.0f;  // -log2(10000)/64
  float f1 = exp2f(c0 * (float)(d >> 1));
  float f2 = exp2f(c0 * (float)((d >> 1) + 32));
  float s1, c1, s2, c2;
  __sincosf(pf * f1, &s1, &c1);
  __sincosf(pf * f2, &s2, &c2);
  out[base]      = f2bf(lo * c1 - hi * s1);
  out[base + 64] = f2bf(hi * c2 + lo * s2);
}

// ---------------- Flash attention (causal, GQA), bf16 MFMA ----------------
// grid (8 qtiles, 32 heads, 4 batch); block 256 = 4 waves; wave owns 32 q-rows.
// K-tiles of 32 keys. S=QK^T via 16x16x32 MFMA; P roundtrip via LDS; PV via MFMA.
#define ATT_SCALE 0.08838834764831843f
__global__ __launch_bounds__(256) void attn_k(const unsigned short* __restrict__ Qp,
                                              const unsigned short* __restrict__ Kp,
                                              const unsigned short* __restrict__ Vp,
                                              unsigned short* __restrict__ Op) {
  const int qt = blockIdx.x, h = blockIdx.y, b = blockIdx.z;
  const int kvh = h >> 2;
  const int tid = threadIdx.x, wave = tid >> 6, lane = tid & 63;
  const int m16 = lane & 15, quad = lane >> 4;
  const int qbase = qt * 128;
  const int wq0 = wave * 32;

  __shared__ unsigned short Ks[32][128];   // [key][d], chunks xor (key&7)
  __shared__ unsigned short Vt[128][32];   // [d][key], chunks xor ((d>>1)&3)
  __shared__ unsigned short Ps[4][32][32]; // per-wave P, chunks xor ((qrow>>1)&3)

  // preload Q fragments (A-operand): rows i*16+m16, k = kk*32+quad*8..+7
  bf16x8 qa[2][4];
#pragma unroll
  for (int i = 0; i < 2; ++i) {
    long tok = (long)(b * SEQ + qbase + wq0 + i * 16 + m16);
    const unsigned short* qrow = Qp + tok * (NHQ * HDIM) + h * HDIM;
#pragma unroll
    for (int kk = 0; kk < 4; ++kk)
      qa[i][kk] = *(const bf16x8*)(qrow + kk * 32 + quad * 8);
  }

  f32x4 o[2][8] = {};
  float mrow[2][4], lrow[2][4];
#pragma unroll
  for (int i = 0; i < 2; ++i)
#pragma unroll
    for (int r = 0; r < 4; ++r) { mrow[i][r] = -1e30f; lrow[i][r] = 0.f; }

  const int nkt = qt * 4 + 4;
  for (int kt = 0; kt < nkt; ++kt) {
    __syncthreads();
    // stage K[32][128] and V transposed Vt[128][32]
#pragma unroll
    for (int l = tid; l < 512; l += 256) {
      int row = l >> 4, seg = l & 15;
      long tok = (long)(b * SEQ + kt * 32 + row);
      uint4 dk = *(const uint4*)(Kp + tok * (NKVH * HDIM) + kvh * HDIM + seg * 8);
      *(uint4*)(&Ks[row][(seg ^ (row & 7)) * 8]) = dk;
      uint4 dv = *(const uint4*)(Vp + tok * (NKVH * HDIM) + kvh * HDIM + seg * 8);
      const unsigned short* pv = (const unsigned short*)&dv;
#pragma unroll
      for (int e = 0; e < 8; ++e) {
        int d = seg * 8 + e;
        Vt[d][(((row >> 3) ^ ((d >> 1) & 3)) * 8) + (row & 7)] = pv[e];
      }
    }
    __syncthreads();

    const bool active = (kt * 32) <= (qbase + wq0 + 31);
    float pmat[2][2][4];
    if (active) {
      bf16x8 kb[2][4];
#pragma unroll
      for (int j = 0; j < 2; ++j) {
        int row = j * 16 + m16;
#pragma unroll
        for (int kk = 0; kk < 4; ++kk)
          kb[j][kk] = *(const bf16x8*)(&Ks[row][((kk * 4 + quad) ^ (row & 7)) * 8]);
      }
      f32x4 s[2][2] = {};
#pragma unroll
      for (int kk = 0; kk < 4; ++kk)
#pragma unroll
        for (int i = 0; i < 2; ++i)
#pragma unroll
          for (int j = 0; j < 2; ++j)
            s[i][j] = __builtin_amdgcn_mfma_f32_16x16x32_bf16(qa[i][kk], kb[j][kk], s[i][j], 0, 0, 0);
#pragma unroll
      for (int i = 0; i < 2; ++i) {
#pragma unroll
        for (int r = 0; r < 4; ++r) {
          int qi = qbase + wq0 + i * 16 + quad * 4 + r;
          float v0 = s[i][0][r] * ATT_SCALE;
          float v1 = s[i][1][r] * ATT_SCALE;
          if (kt * 32 + m16 > qi)      v0 = -1e30f;
          if (kt * 32 + 16 + m16 > qi) v1 = -1e30f;
          float mx = fmaxf(v0, v1);
          mx = fmaxf(mx, __shfl_xor(mx, 1));
          mx = fmaxf(mx, __shfl_xor(mx, 2));
          mx = fmaxf(mx, __shfl_xor(mx, 4));
          mx = fmaxf(mx, __shfl_xor(mx, 8));
          float mold = mrow[i][r];
          float mnew = fmaxf(mold, mx);
          float alpha = __expf(mold - mnew);
          float p0 = __expf(v0 - mnew), p1 = __expf(v1 - mnew);
          float rs = p0 + p1;
          rs += __shfl_xor(rs, 1); rs += __shfl_xor(rs, 2);
          rs += __shfl_xor(rs, 4); rs += __shfl_xor(rs, 8);
          lrow[i][r] = lrow[i][r] * alpha + rs;
          mrow[i][r] = mnew;
#pragma unroll
          for (int n = 0; n < 8; ++n) o[i][n][r] *= alpha;
          pmat[i][0][r] = p0; pmat[i][1][r] = p1;
        }
      }
    } else {
#pragma unroll
      for (int i = 0; i < 2; ++i)
#pragma unroll
        for (int j = 0; j < 2; ++j)
#pragma unroll
          for (int r = 0; r < 4; ++r) pmat[i][j][r] = 0.f;
    }
    // P -> LDS (C-layout indices), then read back in A-operand layout
#pragma unroll
    for (int i = 0; i < 2; ++i)
#pragma unroll
      for (int j = 0; j < 2; ++j)
#pragma unroll
        for (int r = 0; r < 4; ++r) {
          int qrow = i * 16 + quad * 4 + r;
          int col = j * 16 + m16;
          Ps[wave][qrow][(((col >> 3) ^ ((qrow >> 1) & 3)) * 8) + (col & 7)] = f2bf(pmat[i][j][r]);
        }
    __syncthreads();
    bf16x8 pa[2];
#pragma unroll
    for (int i = 0; i < 2; ++i) {
      int row = i * 16 + m16;
      pa[i] = *(const bf16x8*)(&Ps[wave][row][(quad ^ ((row >> 1) & 3)) * 8]);
    }
    bf16x8 vbf[8];
#pragma unroll
    for (int n = 0; n < 8; ++n) {
      int row = n * 16 + m16;
      vbf[n] = *(const bf16x8*)(&Vt[row][(quad ^ ((row >> 1) & 3)) * 8]);
    }
#pragma unroll
    for (int i = 0; i < 2; ++i)
#pragma unroll
      for (int n = 0; n < 8; ++n)
        o[i][n] = __builtin_amdgcn_mfma_f32_16x16x32_bf16(pa[i], vbf[n], o[i][n], 0, 0, 0);
  }

  // epilogue: normalize and store bf16
#pragma unroll
  for (int i = 0; i < 2; ++i) {
#pragma unroll
    for (int r = 0; r < 4; ++r) {
      float inv = 1.0f / lrow[i][r];
      long tok = (long)(b * SEQ + qbase + wq0 + i * 16 + quad * 4 + r);
      unsigned short* orow = Op + tok * (NHQ * HDIM) + h * HDIM;
#pragma unroll
      for (int n = 0; n < 8; ++n)
        orow[n * 16 + m16] = f2bf(o[i][n][r] * inv);
    }
  }
}

// ---------------- launch ----------------
extern "C" void kernel_launch(void* const* d_in, const int* in_sizes, int n_in,
                              void* d_out, int out_size, void* d_ws, size_t ws_size,
                              hipStream_t stream) {
  (void)in_sizes; (void)n_in; (void)out_size; (void)ws_size;
  const float* x  = (const float*)d_in[0];
  const int* pos  = (const int*)d_in[1];
  const float* wq = (const float*)d_in[3];
  const float* wk = (const float*)d_in[4];
  const float* wv = (const float*)d_in[5];
  const float* wo = (const float*)d_in[6];
  float* out = (float*)d_out;

  char* ws = (char*)d_ws;
  unsigned short* xb  = (unsigned short*)(ws);                      // 32MB bf16 x
  unsigned short* wb  = (unsigned short*)(ws + (32ll << 20));       // 32MB weight slot (reused)
  float*          qf  = (float*)(ws + (64ll << 20));                // 64MB q fp32
  float*          kf  = (float*)(ws + (128ll << 20));               // 16MB k fp32
  unsigned short* qr  = (unsigned short*)(ws + (144ll << 20));      // 32MB q roped bf16
  unsigned short* kr  = (unsigned short*)(ws + (176ll << 20));      // 8MB  k roped bf16
  unsigned short* vb_ = (unsigned short*)(ws + (184ll << 20));      // 8MB  v bf16
  unsigned short* ao  = (unsigned short*)(ws + (192ll << 20));      // 32MB attn out bf16

  cast_bf16_k<<<16384, 256, 0, stream>>>(x, xb, 4194304);
  cast_bf16_k<<<16384, 256, 0, stream>>>(wq, wb, 4194304);
  gemm_bt_k<false><<<dim3(32, 32), 256, 0, stream>>>(xb, wb, qf, 4096, 4096, 4096);
  cast_bf16_k<<<4096, 256, 0, stream>>>(wk, wb, 1048576);
  gemm_bt_k<false><<<dim3(8, 32), 256, 0, stream>>>(xb, wb, kf, 4096, 1024, 4096);
  cast_bf16_k<<<4096, 256, 0, stream>>>(wv, wb, 1048576);
  gemm_bt_k<true><<<dim3(8, 32), 256, 0, stream>>>(xb, wb, vb_, 4096, 1024, 4096);
  rope_k<32><<<32768, 256, 0, stream>>>(qf, qr, pos);
  rope_k<8><<<8192, 256, 0, stream>>>(kf, kr, pos);
  attn_k<<<dim3(8, 32, 4), 256, 0, stream>>>(qr, kr, vb_, ao);
  cast_bf16_k<<<16384, 256, 0, stream>>>(wo, wb, 4194304);
  gemm_bt_k<false><<<dim3(32, 32), 256, 0, stream>>>(ao, wb, out, 4096, 4096, 4096);
}

// Round 2
// 918.435 us; speedup vs baseline: 1.3951x; 1.3951x over previous
//
#include <hip/hip_runtime.h>
#include <hip/hip_bf16.h>
#include <math.h>

#define T_TOK 4096
#define HID   4096
#define NHQ   32
#define NKVH  8
#define HDIM  128
#define SEQ   1024
#define NBATCH 4

typedef __attribute__((ext_vector_type(8))) short bf16x8;
typedef __attribute__((ext_vector_type(4))) float f32x4;

__device__ __forceinline__ unsigned short f2bf(float f) {
  union { float f; unsigned int u; } x; x.f = f;
  unsigned int r = x.u + 0x7FFFu + ((x.u >> 16) & 1u);
  return (unsigned short)(r >> 16);
}

// async global->LDS, 16B per lane. LDS dest must be wave-uniform base; HW adds lane*16.
#define GLOAD_LDS16(gp, lp)                                                        \
  __builtin_amdgcn_global_load_lds(                                                \
      (__attribute__((address_space(1))) void*)(unsigned long long)(const void*)(gp), \
      (__attribute__((address_space(3))) void*)(unsigned long long)(const void*)(lp), \
      16, 0, 0)

// ---------------- cast fp32 -> bf16, 4 elems/thread ----------------
__global__ __launch_bounds__(256) void cast_bf16_k(const float* __restrict__ in,
                                                   unsigned short* __restrict__ out,
                                                   int n4) {
  int i = blockIdx.x * 256 + threadIdx.x;
  if (i >= n4) return;
  float4 f = ((const float4*)in)[i];
  ushort4 o;
  o.x = f2bf(f.x); o.y = f2bf(f.y); o.z = f2bf(f.z); o.w = f2bf(f.w);
  ((ushort4*)out)[i] = o;
}

// ---------------- GEMM: C[M,N] = A[M,K] @ B[N,K]^T (bf16 in, fp32/bf16 out) ----
// 128x128 tile, BK=64, 4 waves of 64x64, 16x16x32 bf16 MFMA.
// Staging via global_load_lds width=16; XOR swizzle applied on the GLOBAL source
// address so the LDS destination stays linear (wave base + lane*16).
template<bool OUT_BF16>
__global__ __launch_bounds__(256) void gemm_bt_k(const unsigned short* __restrict__ A,
                                                 const unsigned short* __restrict__ B,
                                                 void* __restrict__ Cv,
                                                 int M, int N, int K) {
  __shared__ unsigned short As[128][64];
  __shared__ unsigned short Bs[128][64];
  const int tid  = threadIdx.x;
  const int lane = tid & 63;
  const int wave = tid >> 6;
  const int m16  = lane & 15, quad = lane >> 4;
  const int wm   = (wave >> 1) * 64, wn = (wave & 1) * 64;
  const long rowBase = (long)blockIdx.y * 128;
  const long colBase = (long)blockIdx.x * 128;

  f32x4 acc[4][4] = {};

  for (int k0 = 0; k0 < K; k0 += 64) {
    __syncthreads();
#pragma unroll
    for (int it = 0; it < 4; ++it) {
      int c = it * 256 + tid;
      int row = c >> 3;
      int sg = (c & 7) ^ (row & 7);
      int ldsoff = (it * 256 + wave * 64) * 8;  // shorts
      GLOAD_LDS16(A + (rowBase + row) * K + k0 + sg * 8, ((unsigned short*)As) + ldsoff);
      GLOAD_LDS16(B + (colBase + row) * K + k0 + sg * 8, ((unsigned short*)Bs) + ldsoff);
    }
    __syncthreads();
#pragma unroll
    for (int kk = 0; kk < 2; ++kk) {
      bf16x8 af[4], bfr[4];
#pragma unroll
      for (int i = 0; i < 4; ++i) {
        int row = wm + i * 16 + m16;
        af[i] = *(const bf16x8*)(&As[row][((kk * 4 + quad) ^ (row & 7)) * 8]);
      }
#pragma unroll
      for (int j = 0; j < 4; ++j) {
        int row = wn + j * 16 + m16;
        bfr[j] = *(const bf16x8*)(&Bs[row][((kk * 4 + quad) ^ (row & 7)) * 8]);
      }
#pragma unroll
      for (int i = 0; i < 4; ++i)
#pragma unroll
        for (int j = 0; j < 4; ++j)
          acc[i][j] = __builtin_amdgcn_mfma_f32_16x16x32_bf16(af[i], bfr[j], acc[i][j], 0, 0, 0);
    }
  }
#pragma unroll
  for (int i = 0; i < 4; ++i) {
#pragma unroll
    for (int j = 0; j < 4; ++j) {
      long r0 = rowBase + wm + i * 16 + quad * 4;
      long c  = colBase + wn + j * 16 + m16;
#pragma unroll
      for (int r = 0; r < 4; ++r) {
        float v = acc[i][j][r];
        if (OUT_BF16) ((unsigned short*)Cv)[(r0 + r) * N + c] = f2bf(v);
        else          ((float*)Cv)[(r0 + r) * N + c] = v;
      }
    }
  }
}

// ---------------- RoPE (faithful: repeat-by-2 freqs + rotate-half) ------------
template<int NHEADS>
__global__ __launch_bounds__(256) void rope_k(const float* __restrict__ in,
                                              unsigned short* __restrict__ out,
                                              const int* __restrict__ pos) {
  int idx = blockIdx.x * 256 + threadIdx.x;  // exact grid: T*NHEADS*64
  int d  = idx & 63;
  int th = idx >> 6;
  int t  = th / NHEADS;
  int hh = th - t * NHEADS;
  int p  = pos[t];
  p = p < 0 ? 0 : (p > SEQ - 1 ? SEQ - 1 : p);
  float pf = (float)p;
  long base = (long)t * (NHEADS * HDIM) + hh * HDIM + d;
  float lo = in[base], hi = in[base + 64];
  const float c0 = -13.287712379549449f / 64.0f;  // -log2(10000)/64
  float f1 = exp2f(c0 * (float)(d >> 1));
  float f2 = exp2f(c0 * (float)((d >> 1) + 32));
  float s1, c1, s2, c2;
  __sincosf(pf * f1, &s1, &c1);
  __sincosf(pf * f2, &s2, &c2);
  out[base]      = f2bf(lo * c1 - hi * s1);
  out[base + 64] = f2bf(hi * c2 + lo * s2);
}

// ---------------- Flash attention (causal, GQA), bf16 MFMA ----------------
// grid (4 pairs, 32 heads, 4 batch); block 256 = 4 waves; wave owns 32 q-rows.
// Each block processes q-tiles (7-p) then (p): exactly 18 64-key K-tiles each
// -> perfectly balanced. K staged async; V transposed with conflict-free scatter
// (key = lane, additive chunk rotation pc = ((key>>3)+d)&7).
#define ATT_SCALE 0.08838834764831843f
__global__ __launch_bounds__(256) void attn_k(const unsigned short* __restrict__ Qp,
                                              const unsigned short* __restrict__ Kp,
                                              const unsigned short* __restrict__ Vp,
                                              unsigned short* __restrict__ Op) {
  const int pr = blockIdx.x, h = blockIdx.y, b = blockIdx.z;
  const int kvh = h >> 2;
  const int tid = threadIdx.x, wave = tid >> 6, lane = tid & 63;
  const int m16 = lane & 15, quad = lane >> 4;

  __shared__ unsigned short Ks[64][128];   // [key][d], 16 chunks/row, 3-bit xor swizzle
  __shared__ unsigned short Vt[128][64];   // [d][key], 8 chunks/row, additive rotation
  __shared__ unsigned short Ps[4][32][64]; // per-wave P, additive rotation

  for (int pass = 0; pass < 2; ++pass) {
    const int qt = pass ? pr : (7 - pr);
    const int qbase = qt * 128;
    const int wq_lo = qbase + wave * 32;

    // Q fragments (A-operand): rows i*16+m16, k = kk*32+quad*8..+7
    bf16x8 qa[2][4];
#pragma unroll
    for (int i = 0; i < 2; ++i) {
      const unsigned short* qrow =
          Qp + (long)(b * SEQ + wq_lo + i * 16 + m16) * (NHQ * HDIM) + h * HDIM;
#pragma unroll
      for (int kk = 0; kk < 4; ++kk)
        qa[i][kk] = *(const bf16x8*)(qrow + kk * 32 + quad * 8);
    }

    f32x4 o[2][8] = {};
    float mrow[2][4], lrow[2][4];
#pragma unroll
    for (int i = 0; i < 2; ++i)
#pragma unroll
      for (int r = 0; r < 4; ++r) { mrow[i][r] = -1e30f; lrow[i][r] = 0.f; }

    const int nkt = qt * 2 + 2;
    for (int kt = 0; kt < nkt; ++kt) {
      __syncthreads();  // prior tile's LDS consumers done (also guards pass switch)
      const unsigned short* Kbase =
          Kp + (long)(b * SEQ + kt * 64) * (NKVH * HDIM) + kvh * HDIM;
      const unsigned short* Vbase =
          Vp + (long)(b * SEQ + kt * 64) * (NKVH * HDIM) + kvh * HDIM;
      // K: async, LDS-linear, source-permuted segs
#pragma unroll
      for (int it = 0; it < 4; ++it) {
        int c = it * 256 + tid;
        int row = c >> 4, psg = c & 15;
        int sg = (psg & 8) | ((psg & 7) ^ (row & 7));
        GLOAD_LDS16(Kbase + row * (NKVH * HDIM) + sg * 8,
                    ((unsigned short*)Ks) + (it * 256 + wave * 64) * 8);
      }
      // V: manual transpose scatter, key = lane (conflict-free banks)
#pragma unroll
      for (int it = 0; it < 4; ++it) {
        int seg = it * 4 + wave;  // wave-uniform
        uint4 dv = *(const uint4*)(Vbase + lane * (NKVH * HDIM) + seg * 8);
        const unsigned short* pv = (const unsigned short*)&dv;
#pragma unroll
        for (int e = 0; e < 8; ++e) {
          int d = seg * 8 + e;
          Vt[d][((((lane >> 3) + d) & 7) * 8) + (lane & 7)] = pv[e];
        }
      }
      __syncthreads();

      const bool active = (kt * 64) <= (wq_lo + 31);
      if (active) {
        // ---- QK^T ----
        f32x4 s4[2][4] = {};
#pragma unroll
        for (int kk = 0; kk < 4; ++kk) {
          bf16x8 kbf[4];
#pragma unroll
          for (int j = 0; j < 4; ++j) {
            int row = j * 16 + m16;
            int cl = kk * 4 + quad;
            int ps = (cl & 8) | ((cl & 7) ^ (row & 7));
            kbf[j] = *(const bf16x8*)(&Ks[row][ps * 8]);
          }
#pragma unroll
          for (int i = 0; i < 2; ++i)
#pragma unroll
            for (int j = 0; j < 4; ++j)
              s4[i][j] = __builtin_amdgcn_mfma_f32_16x16x32_bf16(qa[i][kk], kbf[j], s4[i][j], 0, 0, 0);
        }
        // ---- online softmax + P write ----
        const bool full = (kt * 64 + 63) <= wq_lo;
#pragma unroll
        for (int i = 0; i < 2; ++i) {
#pragma unroll
          for (int r = 0; r < 4; ++r) {
            const int qrow = i * 16 + quad * 4 + r;
            const int qi = qbase + wave * 32 + qrow;
            float v[4];
#pragma unroll
            for (int j = 0; j < 4; ++j) {
              v[j] = s4[i][j][r] * ATT_SCALE;
              if (!full && (kt * 64 + j * 16 + m16 > qi)) v[j] = -1e30f;
            }
            float mx = fmaxf(fmaxf(v[0], v[1]), fmaxf(v[2], v[3]));
            mx = fmaxf(mx, __shfl_xor(mx, 1));
            mx = fmaxf(mx, __shfl_xor(mx, 2));
            mx = fmaxf(mx, __shfl_xor(mx, 4));
            mx = fmaxf(mx, __shfl_xor(mx, 8));
            float mold = mrow[i][r];
            float mnew = fmaxf(mold, mx);
            float alpha = __expf(mold - mnew);
            float rs = 0.f;
#pragma unroll
            for (int j = 0; j < 4; ++j) {
              float pj = __expf(v[j] - mnew);
              rs += pj;
              int col = j * 16 + m16;
              Ps[wave][qrow][((((col >> 3) + qrow) & 7) * 8) + (col & 7)] = f2bf(pj);
            }
            rs += __shfl_xor(rs, 1); rs += __shfl_xor(rs, 2);
            rs += __shfl_xor(rs, 4); rs += __shfl_xor(rs, 8);
            lrow[i][r] = lrow[i][r] * alpha + rs;
            mrow[i][r] = mnew;
#pragma unroll
            for (int n = 0; n < 8; ++n) o[i][n][r] *= alpha;
          }
        }
        // ---- PV (wave-private Ps: no barrier needed, lgkmcnt orders RAW) ----
#pragma unroll
        for (int kk = 0; kk < 2; ++kk) {
          bf16x8 pa[2], vb[8];
#pragma unroll
          for (int i = 0; i < 2; ++i) {
            int row = i * 16 + m16;
            pa[i] = *(const bf16x8*)(&Ps[wave][row][(((kk * 4 + quad) + row) & 7) * 8]);
          }
#pragma unroll
          for (int n = 0; n < 8; ++n) {
            int row = n * 16 + m16;
            vb[n] = *(const bf16x8*)(&Vt[row][(((kk * 4 + quad) + row) & 7) * 8]);
          }
#pragma unroll
          for (int i = 0; i < 2; ++i)
#pragma unroll
            for (int n = 0; n < 8; ++n)
              o[i][n] = __builtin_amdgcn_mfma_f32_16x16x32_bf16(pa[i], vb[n], o[i][n], 0, 0, 0);
        }
      }
    }
    // epilogue: normalize and store bf16
#pragma unroll
    for (int i = 0; i < 2; ++i) {
#pragma unroll
      for (int r = 0; r < 4; ++r) {
        float inv = 1.0f / lrow[i][r];
        unsigned short* orow =
            Op + (long)(b * SEQ + wq_lo + i * 16 + quad * 4 + r) * (NHQ * HDIM) + h * HDIM;
#pragma unroll
        for (int n = 0; n < 8; ++n)
          orow[n * 16 + m16] = f2bf(o[i][n][r] * inv);
      }
    }
  }
}

// ---------------- launch ----------------
extern "C" void kernel_launch(void* const* d_in, const int* in_sizes, int n_in,
                              void* d_out, int out_size, void* d_ws, size_t ws_size,
                              hipStream_t stream) {
  (void)in_sizes; (void)n_in; (void)out_size; (void)ws_size;
  const float* x  = (const float*)d_in[0];
  const int* pos  = (const int*)d_in[1];
  const float* wq = (const float*)d_in[3];
  const float* wk = (const float*)d_in[4];
  const float* wv = (const float*)d_in[5];
  const float* wo = (const float*)d_in[6];
  float* out = (float*)d_out;

  char* ws = (char*)d_ws;
  unsigned short* xb  = (unsigned short*)(ws);                      // 32MB bf16 x
  unsigned short* wb  = (unsigned short*)(ws + (32ll << 20));       // 32MB weight slot (reused)
  float*          qf  = (float*)(ws + (64ll << 20));                // 64MB q fp32
  float*          kf  = (float*)(ws + (128ll << 20));               // 16MB k fp32
  unsigned short* qr  = (unsigned short*)(ws + (144ll << 20));      // 32MB q roped bf16
  unsigned short* kr  = (unsigned short*)(ws + (176ll << 20));      // 8MB  k roped bf16
  unsigned short* vb_ = (unsigned short*)(ws + (184ll << 20));      // 8MB  v bf16
  unsigned short* ao  = (unsigned short*)(ws + (192ll << 20));      // 32MB attn out bf16

  cast_bf16_k<<<16384, 256, 0, stream>>>(x, xb, 4194304);
  cast_bf16_k<<<16384, 256, 0, stream>>>(wq, wb, 4194304);
  gemm_bt_k<false><<<dim3(32, 32), 256, 0, stream>>>(xb, wb, qf, 4096, 4096, 4096);
  cast_bf16_k<<<4096, 256, 0, stream>>>(wk, wb, 1048576);
  gemm_bt_k<false><<<dim3(8, 32), 256, 0, stream>>>(xb, wb, kf, 4096, 1024, 4096);
  cast_bf16_k<<<4096, 256, 0, stream>>>(wv, wb, 1048576);
  gemm_bt_k<true><<<dim3(8, 32), 256, 0, stream>>>(xb, wb, vb_, 4096, 1024, 4096);
  rope_k<32><<<32768, 256, 0, stream>>>(qf, qr, pos);
  rope_k<8><<<8192, 256, 0, stream>>>(kf, kr, pos);
  attn_k<<<dim3(4, 32, 4), 256, 0, stream>>>(qr, kr, vb_, ao);
  cast_bf16_k<<<16384, 256, 0, stream>>>(wo, wb, 4194304);
  gemm_bt_k<false><<<dim3(32, 32), 256, 0, stream>>>(ao, wb, out, 4096, 4096, 4096);
}

// Round 3
// 822.074 us; speedup vs baseline: 1.5586x; 1.1172x over previous
//
#include <hip/hip_runtime.h>
#include <hip/hip_bf16.h>
#include <math.h>

#define T_TOK 4096
#define HID   4096
#define NHQ   32
#define NKVH  8
#define HDIM  128
#define SEQ   1024
#define NBATCH 4

typedef __attribute__((ext_vector_type(8))) short bf16x8;
typedef __attribute__((ext_vector_type(4))) float f32x4;

__device__ __forceinline__ unsigned short f2bf(float f) {
  union { float f; unsigned int u; } x; x.f = f;
  unsigned int r = x.u + 0x7FFFu + ((x.u >> 16) & 1u);
  return (unsigned short)(r >> 16);
}

// async global->LDS, 16B per lane. LDS dest must be wave-uniform base; HW adds lane*16.
#define GLOAD_LDS16(gp, lp)                                                        \
  __builtin_amdgcn_global_load_lds(                                                \
      (__attribute__((address_space(1))) void*)(unsigned long long)(const void*)(gp), \
      (__attribute__((address_space(3))) void*)(unsigned long long)(const void*)(lp), \
      16, 0, 0)

// ---------------- cast fp32 -> bf16, 4 elems/thread ----------------
__global__ __launch_bounds__(256) void cast_bf16_k(const float* __restrict__ in,
                                                   unsigned short* __restrict__ out,
                                                   int n4) {
  int i = blockIdx.x * 256 + threadIdx.x;
  if (i >= n4) return;
  float4 f = ((const float4*)in)[i];
  ushort4 o;
  o.x = f2bf(f.x); o.y = f2bf(f.y); o.z = f2bf(f.z); o.w = f2bf(f.w);
  ((ushort4*)out)[i] = o;
}

// ---------------- GEMM core: C[M,N] = A[M,K] @ B[N,K]^T (bf16 in) -------------
// 128x128 tile, BK=64, 4 waves. Wave w owns rows (w>>1)*64..+63 and the column
// set {(w&1)*32..+31} U {(w&1)*32+64..+95} so the RoPE rotate-half partner
// (d, d+64) lives in the same lane at acc j and j+2.
// FUSED=true: N=6144 QKV projection; epilogue applies RoPE (q/k heads) and
// scatters bf16 into qr/kr/vb. FUSED=false: plain fp32 C store (final output).
template<bool FUSED>
__global__ __launch_bounds__(256) void gemm_core(const unsigned short* __restrict__ A,
                                                 const unsigned short* __restrict__ B,
                                                 float* __restrict__ C,
                                                 const int* __restrict__ pos,
                                                 unsigned short* __restrict__ qr,
                                                 unsigned short* __restrict__ kr,
                                                 unsigned short* __restrict__ vbuf,
                                                 int N, int K) {
  __shared__ unsigned short As[128][64];
  __shared__ unsigned short Bs[128][64];
  const int tid  = threadIdx.x;
  const int lane = tid & 63;
  const int wave = tid >> 6;
  const int m16  = lane & 15, quad = lane >> 4;
  const int wm   = (wave >> 1) * 64;
  const int cb   = (wave & 1) * 32;  // column sub-base within the 128-col tile
  const long rowBase = (long)blockIdx.y * 128;
  const long colBase = (long)blockIdx.x * 128;

  f32x4 acc[4][4] = {};

  for (int k0 = 0; k0 < K; k0 += 64) {
    __syncthreads();
#pragma unroll
    for (int it = 0; it < 4; ++it) {
      int c = it * 256 + tid;
      int row = c >> 3;
      int sg = (c & 7) ^ (row & 7);
      int ldsoff = (it * 256 + wave * 64) * 8;  // shorts
      GLOAD_LDS16(A + (rowBase + row) * K + k0 + sg * 8, ((unsigned short*)As) + ldsoff);
      GLOAD_LDS16(B + (colBase + row) * K + k0 + sg * 8, ((unsigned short*)Bs) + ldsoff);
    }
    __syncthreads();
#pragma unroll
    for (int kk = 0; kk < 2; ++kk) {
      bf16x8 af[4], bfr[4];
#pragma unroll
      for (int i = 0; i < 4; ++i) {
        int row = wm + i * 16 + m16;
        af[i] = *(const bf16x8*)(&As[row][((kk * 4 + quad) ^ (row & 7)) * 8]);
      }
#pragma unroll
      for (int j = 0; j < 4; ++j) {
        int row = cb + (j & 1) * 16 + (j >> 1) * 64 + m16;
        bfr[j] = *(const bf16x8*)(&Bs[row][((kk * 4 + quad) ^ (row & 7)) * 8]);
      }
#pragma unroll
      for (int i = 0; i < 4; ++i)
#pragma unroll
        for (int j = 0; j < 4; ++j)
          acc[i][j] = __builtin_amdgcn_mfma_f32_16x16x32_bf16(af[i], bfr[j], acc[i][j], 0, 0, 0);
    }
  }

  if (!FUSED) {
#pragma unroll
    for (int i = 0; i < 4; ++i) {
#pragma unroll
      for (int j = 0; j < 4; ++j) {
        long r0 = rowBase + wm + i * 16 + quad * 4;
        long c  = colBase + cb + (j & 1) * 16 + (j >> 1) * 64 + m16;
#pragma unroll
        for (int r = 0; r < 4; ++r)
          C[(r0 + r) * N + c] = acc[i][j][r];
      }
    }
    return;
  }

  // ---- fused epilogue: RoPE (q/k) or plain (v), bf16 scatter ----
  const int n0 = (int)colBase;
  unsigned short* dst;
  int rstride, colofs;
  bool dorope;
  if (n0 < 4096)       { dst = qr;   rstride = NHQ * HDIM;  colofs = n0;        dorope = true; }
  else if (n0 < 5120)  { dst = kr;   rstride = NKVH * HDIM; colofs = n0 - 4096; dorope = true; }
  else                 { dst = vbuf; rstride = NKVH * HDIM; colofs = n0 - 5120; dorope = false; }
  const float c0 = -13.287712379549449f / 64.0f;  // -log2(10000)/64
#pragma unroll
  for (int i = 0; i < 4; ++i) {
#pragma unroll
    for (int r = 0; r < 4; ++r) {
      int grow = (int)rowBase + wm + i * 16 + quad * 4 + r;
      unsigned short* drow = dst + (long)grow * rstride + colofs;
      if (dorope) {
        int p = pos[grow];
        p = p < 0 ? 0 : (p > SEQ - 1 ? SEQ - 1 : p);
        float pf = (float)p;
#pragma unroll
        for (int jj = 0; jj < 2; ++jj) {
          int d = cb + jj * 16 + m16;        // 0..63
          int fi = d >> 1;
          float f1 = exp2f(c0 * (float)fi);
          float f2 = exp2f(c0 * (float)(fi + 32));
          float s1, cc1, s2, cc2;
          __sincosf(pf * f1, &s1, &cc1);
          __sincosf(pf * f2, &s2, &cc2);
          float lo = acc[i][jj][r], hi = acc[i][jj + 2][r];
          drow[d]      = f2bf(lo * cc1 - hi * s1);
          drow[d + 64] = f2bf(hi * cc2 + lo * s2);
        }
      } else {
#pragma unroll
        for (int j = 0; j < 4; ++j) {
          int c = cb + (j & 1) * 16 + (j >> 1) * 64 + m16;
          drow[c] = f2bf(acc[i][j][r]);
        }
      }
    }
  }
}

// ---------------- Flash attention (causal, GQA), bf16 MFMA ----------------
#define ATT_SCALE 0.08838834764831843f
__global__ __launch_bounds__(256) void attn_k(const unsigned short* __restrict__ Qp,
                                              const unsigned short* __restrict__ Kp,
                                              const unsigned short* __restrict__ Vp,
                                              unsigned short* __restrict__ Op) {
  const int pr = blockIdx.x, h = blockIdx.y, b = blockIdx.z;
  const int kvh = h >> 2;
  const int tid = threadIdx.x, wave = tid >> 6, lane = tid & 63;
  const int m16 = lane & 15, quad = lane >> 4;

  __shared__ unsigned short Ks[64][128];   // [key][d], 16 chunks/row, 3-bit xor swizzle
  __shared__ unsigned short Vt[128][64];   // [d][key], 8 chunks/row, additive rotation
  __shared__ unsigned short Ps[4][32][64]; // per-wave P, additive rotation

  for (int pass = 0; pass < 2; ++pass) {
    const int qt = pass ? pr : (7 - pr);
    const int qbase = qt * 128;
    const int wq_lo = qbase + wave * 32;

    bf16x8 qa[2][4];
#pragma unroll
    for (int i = 0; i < 2; ++i) {
      const unsigned short* qrow =
          Qp + (long)(b * SEQ + wq_lo + i * 16 + m16) * (NHQ * HDIM) + h * HDIM;
#pragma unroll
      for (int kk = 0; kk < 4; ++kk)
        qa[i][kk] = *(const bf16x8*)(qrow + kk * 32 + quad * 8);
    }

    f32x4 o[2][8] = {};
    float mrow[2][4], lrow[2][4];
#pragma unroll
    for (int i = 0; i < 2; ++i)
#pragma unroll
      for (int r = 0; r < 4; ++r) { mrow[i][r] = -1e30f; lrow[i][r] = 0.f; }

    const int nkt = qt * 2 + 2;
    for (int kt = 0; kt < nkt; ++kt) {
      __syncthreads();
      const unsigned short* Kbase =
          Kp + (long)(b * SEQ + kt * 64) * (NKVH * HDIM) + kvh * HDIM;
      const unsigned short* Vbase =
          Vp + (long)(b * SEQ + kt * 64) * (NKVH * HDIM) + kvh * HDIM;
#pragma unroll
      for (int it = 0; it < 4; ++it) {
        int c = it * 256 + tid;
        int row = c >> 4, psg = c & 15;
        int sg = (psg & 8) | ((psg & 7) ^ (row & 7));
        GLOAD_LDS16(Kbase + row * (NKVH * HDIM) + sg * 8,
                    ((unsigned short*)Ks) + (it * 256 + wave * 64) * 8);
      }
#pragma unroll
      for (int it = 0; it < 4; ++it) {
        int seg = it * 4 + wave;  // wave-uniform
        uint4 dv = *(const uint4*)(Vbase + lane * (NKVH * HDIM) + seg * 8);
        const unsigned short* pv = (const unsigned short*)&dv;
#pragma unroll
        for (int e = 0; e < 8; ++e) {
          int d = seg * 8 + e;
          Vt[d][((((lane >> 3) + d) & 7) * 8) + (lane & 7)] = pv[e];
        }
      }
      __syncthreads();

      const bool active = (kt * 64) <= (wq_lo + 31);
      if (active) {
        f32x4 s4[2][4] = {};
#pragma unroll
        for (int kk = 0; kk < 4; ++kk) {
          bf16x8 kbf[4];
#pragma unroll
          for (int j = 0; j < 4; ++j) {
            int row = j * 16 + m16;
            int cl = kk * 4 + quad;
            int ps = (cl & 8) | ((cl & 7) ^ (row & 7));
            kbf[j] = *(const bf16x8*)(&Ks[row][ps * 8]);
          }
#pragma unroll
          for (int i = 0; i < 2; ++i)
#pragma unroll
            for (int j = 0; j < 4; ++j)
              s4[i][j] = __builtin_amdgcn_mfma_f32_16x16x32_bf16(qa[i][kk], kbf[j], s4[i][j], 0, 0, 0);
        }
        const bool full = (kt * 64 + 63) <= wq_lo;
#pragma unroll
        for (int i = 0; i < 2; ++i) {
#pragma unroll
          for (int r = 0; r < 4; ++r) {
            const int qrow = i * 16 + quad * 4 + r;
            const int qi = qbase + wave * 32 + qrow;
            float v[4];
#pragma unroll
            for (int j = 0; j < 4; ++j) {
              v[j] = s4[i][j][r] * ATT_SCALE;
              if (!full && (kt * 64 + j * 16 + m16 > qi)) v[j] = -1e30f;
            }
            float mx = fmaxf(fmaxf(v[0], v[1]), fmaxf(v[2], v[3]));
            mx = fmaxf(mx, __shfl_xor(mx, 1));
            mx = fmaxf(mx, __shfl_xor(mx, 2));
            mx = fmaxf(mx, __shfl_xor(mx, 4));
            mx = fmaxf(mx, __shfl_xor(mx, 8));
            float mold = mrow[i][r];
            float mnew = fmaxf(mold, mx);
            float alpha = __expf(mold - mnew);
            float rs = 0.f;
#pragma unroll
            for (int j = 0; j < 4; ++j) {
              float pj = __expf(v[j] - mnew);
              rs += pj;
              int col = j * 16 + m16;
              Ps[wave][qrow][((((col >> 3) + qrow) & 7) * 8) + (col & 7)] = f2bf(pj);
            }
            rs += __shfl_xor(rs, 1); rs += __shfl_xor(rs, 2);
            rs += __shfl_xor(rs, 4); rs += __shfl_xor(rs, 8);
            lrow[i][r] = lrow[i][r] * alpha + rs;
            mrow[i][r] = mnew;
#pragma unroll
            for (int n = 0; n < 8; ++n) o[i][n][r] *= alpha;
          }
        }
#pragma unroll
        for (int kk = 0; kk < 2; ++kk) {
          bf16x8 pa[2], vb[8];
#pragma unroll
          for (int i = 0; i < 2; ++i) {
            int row = i * 16 + m16;
            pa[i] = *(const bf16x8*)(&Ps[wave][row][(((kk * 4 + quad) + row) & 7) * 8]);
          }
#pragma unroll
          for (int n = 0; n < 8; ++n) {
            int row = n * 16 + m16;
            vb[n] = *(const bf16x8*)(&Vt[row][(((kk * 4 + quad) + row) & 7) * 8]);
          }
#pragma unroll
          for (int i = 0; i < 2; ++i)
#pragma unroll
            for (int n = 0; n < 8; ++n)
              o[i][n] = __builtin_amdgcn_mfma_f32_16x16x32_bf16(pa[i], vb[n], o[i][n], 0, 0, 0);
        }
      }
    }
#pragma unroll
    for (int i = 0; i < 2; ++i) {
#pragma unroll
      for (int r = 0; r < 4; ++r) {
        float inv = 1.0f / lrow[i][r];
        unsigned short* orow =
            Op + (long)(b * SEQ + wq_lo + i * 16 + quad * 4 + r) * (NHQ * HDIM) + h * HDIM;
#pragma unroll
        for (int n = 0; n < 8; ++n)
          orow[n * 16 + m16] = f2bf(o[i][n][r] * inv);
      }
    }
  }
}

// ---------------- launch ----------------
extern "C" void kernel_launch(void* const* d_in, const int* in_sizes, int n_in,
                              void* d_out, int out_size, void* d_ws, size_t ws_size,
                              hipStream_t stream) {
  (void)in_sizes; (void)n_in; (void)out_size; (void)ws_size;
  const float* x  = (const float*)d_in[0];
  const int* pos  = (const int*)d_in[1];
  const float* wq = (const float*)d_in[3];
  const float* wk = (const float*)d_in[4];
  const float* wv = (const float*)d_in[5];
  const float* wo = (const float*)d_in[6];
  float* out = (float*)d_out;

  char* ws = (char*)d_ws;
  unsigned short* xb    = (unsigned short*)(ws);                   // 32MB bf16 x
  unsigned short* wqkv  = (unsigned short*)(ws + (32ll << 20));    // 48MB bf16 [wq;wk;wv]
  unsigned short* wob   = (unsigned short*)(ws + (80ll << 20));    // 32MB bf16 wo
  unsigned short* qr    = (unsigned short*)(ws + (112ll << 20));   // 32MB q roped bf16
  unsigned short* kr    = (unsigned short*)(ws + (144ll << 20));   // 8MB  k roped bf16
  unsigned short* vb_   = (unsigned short*)(ws + (152ll << 20));   // 8MB  v bf16
  unsigned short* ao    = (unsigned short*)(ws + (160ll << 20));   // 32MB attn out bf16

  cast_bf16_k<<<16384, 256, 0, stream>>>(x, xb, 4194304);
  cast_bf16_k<<<16384, 256, 0, stream>>>(wq, wqkv, 4194304);
  cast_bf16_k<<<4096, 256, 0, stream>>>(wk, wqkv + 16777216, 1048576);
  cast_bf16_k<<<4096, 256, 0, stream>>>(wv, wqkv + 20971520, 1048576);
  gemm_core<true><<<dim3(48, 32), 256, 0, stream>>>(xb, wqkv, nullptr, pos, qr, kr, vb_, 6144, 4096);
  attn_k<<<dim3(4, 32, 4), 256, 0, stream>>>(qr, kr, vb_, ao);
  cast_bf16_k<<<16384, 256, 0, stream>>>(wo, wob, 4194304);
  gemm_core<false><<<dim3(32, 32), 256, 0, stream>>>(ao, wob, out, nullptr, nullptr, nullptr, nullptr, 4096, 4096);
}

// Round 4
// 805.262 us; speedup vs baseline: 1.5911x; 1.0209x over previous
//
#include <hip/hip_runtime.h>
#include <hip/hip_bf16.h>
#include <math.h>

#define T_TOK 4096
#define HID   4096
#define NHQ   32
#define NKVH  8
#define HDIM  128
#define SEQ   1024
#define NBATCH 4

typedef __attribute__((ext_vector_type(8))) short bf16x8;
typedef __attribute__((ext_vector_type(4))) float f32x4;
typedef __attribute__((ext_vector_type(16))) float f32x16;

__device__ __forceinline__ unsigned short f2bf(float f) {
  union { float f; unsigned int u; } x; x.f = f;
  unsigned int r = x.u + 0x7FFFu + ((x.u >> 16) & 1u);
  return (unsigned short)(r >> 16);
}

// async global->LDS, 16B per lane. LDS dest must be wave-uniform base; HW adds lane*16.
#define GLOAD_LDS16(gp, lp)                                                        \
  __builtin_amdgcn_global_load_lds(                                                \
      (__attribute__((address_space(1))) void*)(unsigned long long)(const void*)(gp), \
      (__attribute__((address_space(3))) void*)(unsigned long long)(const void*)(lp), \
      16, 0, 0)

// ---------------- single fused cast fp32 -> bf16 for all 5 tensors -------------
// segments (in float4 units): x 4194304 | wq 4194304 | wk 1048576 | wv 1048576 | wo 4194304
__global__ __launch_bounds__(256) void cast_all_k(const float* __restrict__ x,
                                                  const float* __restrict__ wq,
                                                  const float* __restrict__ wk,
                                                  const float* __restrict__ wv,
                                                  const float* __restrict__ wo,
                                                  unsigned short* __restrict__ xb,
                                                  unsigned short* __restrict__ wqkv,
                                                  unsigned short* __restrict__ wob) {
  int i = blockIdx.x * 256 + threadIdx.x;  // float4 index, total 14680064
  const float* src; unsigned short* dst; int off;
  if (i < 4194304)       { src = x;  dst = xb;   off = i; }
  else if (i < 8388608)  { src = wq; dst = wqkv; off = i - 4194304; }
  else if (i < 9437184)  { src = wk; dst = wqkv + 16777216; off = i - 8388608; }
  else if (i < 10485760) { src = wv; dst = wqkv + 20971520; off = i - 9437184; }
  else                   { src = wo; dst = wob;  off = i - 10485760; }
  float4 f = ((const float4*)src)[off];
  ushort4 o;
  o.x = f2bf(f.x); o.y = f2bf(f.y); o.z = f2bf(f.z); o.w = f2bf(f.w);
  ((ushort4*)dst)[off] = o;
}

// ---------------- GEMM core: C[M,N] = A[M,K] @ B[N,K]^T (bf16 in) -------------
// 128x128 tile, BK=64, 4 waves, 32x32x16 bf16 MFMA (2x2 acc blocks of 32x32).
// Wave w owns rows (w>>1)*64..+63 and column blocks {cb..cb+31, cb+64..cb+95},
// cb=(w&1)*32, so the RoPE rotate-half partner (d, d+64) lives in the same lane
// at acc j=0 / j=1, and d = cb + (lane&31) is FIXED per lane.
// FUSED=true: N=6144 QKV projection, RoPE fused epilogue, bf16 scatter.
template<bool FUSED>
__global__ __launch_bounds__(256) void gemm_core(const unsigned short* __restrict__ A,
                                                 const unsigned short* __restrict__ B,
                                                 float* __restrict__ C,
                                                 const int* __restrict__ pos,
                                                 unsigned short* __restrict__ qr,
                                                 unsigned short* __restrict__ kr,
                                                 unsigned short* __restrict__ vbuf,
                                                 int N, int K) {
  __shared__ unsigned short As[128][64];
  __shared__ unsigned short Bs[128][64];
  const int tid  = threadIdx.x;
  const int lane = tid & 63;
  const int wave = tid >> 6;
  const int half = lane >> 5;       // 0/1
  const int r31  = lane & 31;
  const int wm   = (wave >> 1) * 64;
  const int cb   = (wave & 1) * 32;
  const long rowBase = (long)blockIdx.y * 128;
  const long colBase = (long)blockIdx.x * 128;

  f32x16 acc[2][2] = {};

  for (int k0 = 0; k0 < K; k0 += 64) {
    __syncthreads();
#pragma unroll
    for (int it = 0; it < 4; ++it) {
      int c = it * 256 + tid;
      int row = c >> 3;
      int sg = (c & 7) ^ (row & 7);
      int ldsoff = (it * 256 + wave * 64) * 8;  // shorts
      GLOAD_LDS16(A + (rowBase + row) * K + k0 + sg * 8, ((unsigned short*)As) + ldsoff);
      GLOAD_LDS16(B + (colBase + row) * K + k0 + sg * 8, ((unsigned short*)Bs) + ldsoff);
    }
    __syncthreads();
#pragma unroll
    for (int kk = 0; kk < 4; ++kk) {
      bf16x8 af[2], bfr[2];
#pragma unroll
      for (int i = 0; i < 2; ++i) {
        int row = wm + i * 32 + r31;
        af[i] = *(const bf16x8*)(&As[row][((kk * 2 + half) ^ (row & 7)) * 8]);
      }
#pragma unroll
      for (int j = 0; j < 2; ++j) {
        int row = cb + j * 64 + r31;
        bfr[j] = *(const bf16x8*)(&Bs[row][((kk * 2 + half) ^ (row & 7)) * 8]);
      }
#pragma unroll
      for (int i = 0; i < 2; ++i)
#pragma unroll
        for (int j = 0; j < 2; ++j)
          acc[i][j] = __builtin_amdgcn_mfma_f32_32x32x16_bf16(af[i], bfr[j], acc[i][j], 0, 0, 0);
    }
  }

  if (!FUSED) {
#pragma unroll
    for (int i = 0; i < 2; ++i)
#pragma unroll
      for (int j = 0; j < 2; ++j) {
        long c = colBase + cb + j * 64 + r31;
#pragma unroll
        for (int reg = 0; reg < 16; ++reg) {
          long row = rowBase + wm + i * 32 + 4 * half + (reg & 3) + 8 * (reg >> 2);
          C[row * N + c] = acc[i][j][reg];
        }
      }
    return;
  }

  // ---- fused epilogue: RoPE (q/k) or plain (v), bf16 scatter ----
  const int n0 = (int)colBase;
  unsigned short* dst;
  int rstride, colofs;
  bool dorope;
  if (n0 < 4096)       { dst = qr;   rstride = NHQ * HDIM;  colofs = n0;        dorope = true; }
  else if (n0 < 5120)  { dst = kr;   rstride = NKVH * HDIM; colofs = n0 - 4096; dorope = true; }
  else                 { dst = vbuf; rstride = NKVH * HDIM; colofs = n0 - 5120; dorope = false; }
  const float c0 = -13.287712379549449f / 64.0f;  // -log2(10000)/64
  const int d = cb + r31;                          // 0..63, fixed per lane
  const float f1 = exp2f(c0 * (float)(d >> 1));
  const float f2 = exp2f(c0 * (float)((d >> 1) + 32));
#pragma unroll
  for (int i = 0; i < 2; ++i) {
#pragma unroll
    for (int reg = 0; reg < 16; ++reg) {
      int grow = (int)rowBase + wm + i * 32 + 4 * half + (reg & 3) + 8 * (reg >> 2);
      unsigned short* drow = dst + (long)grow * rstride + colofs;
      float lo = acc[i][0][reg], hi = acc[i][1][reg];
      if (dorope) {
        int p = pos[grow];
        p = p < 0 ? 0 : (p > SEQ - 1 ? SEQ - 1 : p);
        float pf = (float)p;
        float s1, cc1, s2, cc2;
        __sincosf(pf * f1, &s1, &cc1);
        __sincosf(pf * f2, &s2, &cc2);
        drow[d]      = f2bf(lo * cc1 - hi * s1);
        drow[d + 64] = f2bf(hi * cc2 + lo * s2);
      } else {
        drow[d]      = f2bf(lo);
        drow[d + 64] = f2bf(hi);
      }
    }
  }
}

// ---------------- Flash attention (causal, GQA), bf16 MFMA ----------------
// softmax in exp2 domain: scale folded with log2e.
#define ATT_SCALE_L2 0.12754227022f  // (1/sqrt(128)) * log2(e)
__global__ __launch_bounds__(256) void attn_k(const unsigned short* __restrict__ Qp,
                                              const unsigned short* __restrict__ Kp,
                                              const unsigned short* __restrict__ Vp,
                                              unsigned short* __restrict__ Op) {
  const int pr = blockIdx.x, h = blockIdx.y, b = blockIdx.z;
  const int kvh = h >> 2;
  const int tid = threadIdx.x, wave = tid >> 6, lane = tid & 63;
  const int m16 = lane & 15, quad = lane >> 4;

  __shared__ unsigned short Ks[64][128];   // [key][d], 16 chunks/row, 3-bit xor swizzle
  __shared__ unsigned short Vt[128][64];   // [d][key], 8 chunks/row, additive rotation
  __shared__ unsigned short Ps[4][32][64]; // per-wave P, additive rotation

  for (int pass = 0; pass < 2; ++pass) {
    const int qt = pass ? pr : (7 - pr);
    const int qbase = qt * 128;
    const int wq_lo = qbase + wave * 32;

    bf16x8 qa[2][4];
#pragma unroll
    for (int i = 0; i < 2; ++i) {
      const unsigned short* qrow =
          Qp + (long)(b * SEQ + wq_lo + i * 16 + m16) * (NHQ * HDIM) + h * HDIM;
#pragma unroll
      for (int kk = 0; kk < 4; ++kk)
        qa[i][kk] = *(const bf16x8*)(qrow + kk * 32 + quad * 8);
    }

    f32x4 o[2][8] = {};
    float mrow[2][4], lrow[2][4];
#pragma unroll
    for (int i = 0; i < 2; ++i)
#pragma unroll
      for (int r = 0; r < 4; ++r) { mrow[i][r] = -1e30f; lrow[i][r] = 0.f; }

    const int nkt = qt * 2 + 2;
    for (int kt = 0; kt < nkt; ++kt) {
      __syncthreads();
      const unsigned short* Kbase =
          Kp + (long)(b * SEQ + kt * 64) * (NKVH * HDIM) + kvh * HDIM;
      const unsigned short* Vbase =
          Vp + (long)(b * SEQ + kt * 64) * (NKVH * HDIM) + kvh * HDIM;
#pragma unroll
      for (int it = 0; it < 4; ++it) {
        int c = it * 256 + tid;
        int row = c >> 4, psg = c & 15;
        int sg = (psg & 8) | ((psg & 7) ^ (row & 7));
        GLOAD_LDS16(Kbase + row * (NKVH * HDIM) + sg * 8,
                    ((unsigned short*)Ks) + (it * 256 + wave * 64) * 8);
      }
#pragma unroll
      for (int it = 0; it < 4; ++it) {
        int seg = it * 4 + wave;  // wave-uniform
        uint4 dv = *(const uint4*)(Vbase + lane * (NKVH * HDIM) + seg * 8);
        const unsigned short* pv = (const unsigned short*)&dv;
#pragma unroll
        for (int e = 0; e < 8; ++e) {
          int d = seg * 8 + e;
          Vt[d][((((lane >> 3) + d) & 7) * 8) + (lane & 7)] = pv[e];
        }
      }
      __syncthreads();

      const bool active = (kt * 64) <= (wq_lo + 31);
      if (active) {
        f32x4 s4[2][4] = {};
#pragma unroll
        for (int kk = 0; kk < 4; ++kk) {
          bf16x8 kbf[4];
#pragma unroll
          for (int j = 0; j < 4; ++j) {
            int row = j * 16 + m16;
            int cl = kk * 4 + quad;
            int ps = (cl & 8) | ((cl & 7) ^ (row & 7));
            kbf[j] = *(const bf16x8*)(&Ks[row][ps * 8]);
          }
#pragma unroll
          for (int i = 0; i < 2; ++i)
#pragma unroll
            for (int j = 0; j < 4; ++j)
              s4[i][j] = __builtin_amdgcn_mfma_f32_16x16x32_bf16(qa[i][kk], kbf[j], s4[i][j], 0, 0, 0);
        }
        const bool full = (kt * 64 + 63) <= wq_lo;
#pragma unroll
        for (int i = 0; i < 2; ++i) {
#pragma unroll
          for (int r = 0; r < 4; ++r) {
            const int qrow = i * 16 + quad * 4 + r;
            const int qi = qbase + wave * 32 + qrow;
            float v[4];
#pragma unroll
            for (int j = 0; j < 4; ++j) {
              v[j] = s4[i][j][r] * ATT_SCALE_L2;
              if (!full && (kt * 64 + j * 16 + m16 > qi)) v[j] = -1e30f;
            }
            float mx = fmaxf(fmaxf(v[0], v[1]), fmaxf(v[2], v[3]));
            mx = fmaxf(mx, __shfl_xor(mx, 1));
            mx = fmaxf(mx, __shfl_xor(mx, 2));
            mx = fmaxf(mx, __shfl_xor(mx, 4));
            mx = fmaxf(mx, __shfl_xor(mx, 8));
            float mold = mrow[i][r];
            float mnew = fmaxf(mold, mx);
            float alpha = exp2f(mold - mnew);
            float rs = 0.f;
#pragma unroll
            for (int j = 0; j < 4; ++j) {
              float pj = exp2f(v[j] - mnew);
              rs += pj;
              int col = j * 16 + m16;
              Ps[wave][qrow][((((col >> 3) + qrow) & 7) * 8) + (col & 7)] = f2bf(pj);
            }
            rs += __shfl_xor(rs, 1); rs += __shfl_xor(rs, 2);
            rs += __shfl_xor(rs, 4); rs += __shfl_xor(rs, 8);
            lrow[i][r] = lrow[i][r] * alpha + rs;
            mrow[i][r] = mnew;
#pragma unroll
            for (int n = 0; n < 8; ++n) o[i][n][r] *= alpha;
          }
        }
#pragma unroll
        for (int kk = 0; kk < 2; ++kk) {
          bf16x8 pa[2], vb[8];
#pragma unroll
          for (int i = 0; i < 2; ++i) {
            int row = i * 16 + m16;
            pa[i] = *(const bf16x8*)(&Ps[wave][row][(((kk * 4 + quad) + row) & 7) * 8]);
          }
#pragma unroll
          for (int n = 0; n < 8; ++n) {
            int row = n * 16 + m16;
            vb[n] = *(const bf16x8*)(&Vt[row][(((kk * 4 + quad) + row) & 7) * 8]);
          }
#pragma unroll
          for (int i = 0; i < 2; ++i)
#pragma unroll
            for (int n = 0; n < 8; ++n)
              o[i][n] = __builtin_amdgcn_mfma_f32_16x16x32_bf16(pa[i], vb[n], o[i][n], 0, 0, 0);
        }
      }
    }
#pragma unroll
    for (int i = 0; i < 2; ++i) {
#pragma unroll
      for (int r = 0; r < 4; ++r) {
        float inv = 1.0f / lrow[i][r];
        unsigned short* orow =
            Op + (long)(b * SEQ + wq_lo + i * 16 + quad * 4 + r) * (NHQ * HDIM) + h * HDIM;
#pragma unroll
        for (int n = 0; n < 8; ++n)
          orow[n * 16 + m16] = f2bf(o[i][n][r] * inv);
      }
    }
  }
}

// ---------------- launch ----------------
extern "C" void kernel_launch(void* const* d_in, const int* in_sizes, int n_in,
                              void* d_out, int out_size, void* d_ws, size_t ws_size,
                              hipStream_t stream) {
  (void)in_sizes; (void)n_in; (void)out_size; (void)ws_size;
  const float* x  = (const float*)d_in[0];
  const int* pos  = (const int*)d_in[1];
  const float* wq = (const float*)d_in[3];
  const float* wk = (const float*)d_in[4];
  const float* wv = (const float*)d_in[5];
  const float* wo = (const float*)d_in[6];
  float* out = (float*)d_out;

  char* ws = (char*)d_ws;
  unsigned short* xb    = (unsigned short*)(ws);                   // 32MB bf16 x
  unsigned short* wqkv  = (unsigned short*)(ws + (32ll << 20));    // 48MB bf16 [wq;wk;wv]
  unsigned short* wob   = (unsigned short*)(ws + (80ll << 20));    // 32MB bf16 wo
  unsigned short* qr    = (unsigned short*)(ws + (112ll << 20));   // 32MB q roped bf16
  unsigned short* kr    = (unsigned short*)(ws + (144ll << 20));   // 8MB  k roped bf16
  unsigned short* vb_   = (unsigned short*)(ws + (152ll << 20));   // 8MB  v bf16
  unsigned short* ao    = (unsigned short*)(ws + (160ll << 20));   // 32MB attn out bf16

  cast_all_k<<<57344, 256, 0, stream>>>(x, wq, wk, wv, wo, xb, wqkv, wob);
  gemm_core<true><<<dim3(48, 32), 256, 0, stream>>>(xb, wqkv, nullptr, pos, qr, kr, vb_, 6144, 4096);
  attn_k<<<dim3(4, 32, 4), 256, 0, stream>>>(qr, kr, vb_, ao);
  gemm_core<false><<<dim3(32, 32), 256, 0, stream>>>(ao, wob, out, nullptr, nullptr, nullptr, nullptr, 4096, 4096);
}